// Round 8
// baseline (211.345 us; speedup 1.0000x reference)
//
#include <hip/hip_runtime.h>

#define NETS   64
#define NNODES 288
#define NHID   256
#define NOUT   32
#define KCON   32
#define NBATCH 1024
#define TILE   32                    // batches per block
#define NPAIR  144
#define ROWB   128                   // 32 f32 = one full 32-bank stripe per row
#define LDSZ   (386 * ROWB)          // 49,408 B -> 3 blocks/CU

#if defined(__has_builtin)
#if __has_builtin(__builtin_amdgcn_permlane16_swap)
#define HAVE_PL16 1
#endif
#if __has_builtin(__builtin_amdgcn_permlane32_swap)
#define HAVE_PL32 1
#endif
#endif

__device__ __forceinline__ float xor16_add(float a) {
#ifdef HAVE_PL16
    auto r = __builtin_amdgcn_permlane16_swap(__float_as_uint(a), __float_as_uint(a),
                                              false, false);
    return __uint_as_float(r[0]) + __uint_as_float(r[1]);
#else
    return a + __shfl_xor(a, 16, 64);
#endif
}
__device__ __forceinline__ float xor32_add(float a) {
#ifdef HAVE_PL32
    auto r = __builtin_amdgcn_permlane32_swap(__float_as_uint(a), __float_as_uint(a),
                                              false, false);
    return __uint_as_float(r[0]) + __uint_as_float(r[1]);
#else
    return a + __shfl_xor(a, 32, 64);
#endif
}

__device__ __forceinline__ unsigned f2bf(float f) {
    unsigned b = __float_as_uint(f);
    return (b + 0x7FFFu + ((b >> 16) & 1u)) >> 16;
}
__device__ __forceinline__ float bf2f(unsigned short u) {
    return __uint_as_float(((unsigned)u) << 16);
}

// ---- prep: meta per-lane-contiguous: meta[net][t][s][kq][j] = {idx*ROWB, w_bits} ----
__global__ __launch_bounds__(256) void prep_meta(const float* __restrict__ W,
                                                 const int* __restrict__ conn,
                                                 int2* __restrict__ meta) {
    int g = blockIdx.x * 256 + threadIdx.x;      // 64*288*32 = 589,824 exact
    int net = g / 9216;
    int rem = g - net * 9216;
    int node = rem >> 5, k = rem & 31;
    int idx = conn[g];                           // 0..385
    float w = W[(size_t)idx * NNODES + node];
    int didx = net * 9216 + (node >> 1) * 64 + (node & 1) * 32 + (k >> 3) * 8 + (k & 7);
    meta[didx] = make_int2(idx * ROWB, __float_as_int(w));
}

// ---- prep: xT[row][batch] f32; rows 0..127 = x^T, 128 = 0.0, 129 = 1.0 ----
__global__ __launch_bounds__(256) void prep_xt(const float* __restrict__ x,
                                               float* __restrict__ xT) {
    int g = blockIdx.x * 256 + threadIdx.x;      // 130*1024 = 133,120 exact
    int r = g >> 10, b = g & 1023;
    float v = (r < 128) ? x[(size_t)b * 128 + r] : ((r == 128) ? 0.0f : 1.0f);
    xT[(size_t)r * NBATCH + b] = v;
}

// ---- main: 1 wave / (net, 32-batch tile); f32 state in LDS; stripe-aligned b128 ----
// lane = kq(2b) | s(1b) | p(3b): 8 k-slots per lane, 4 batches per lane (float4)
template <bool F32OUT>
__global__ __launch_bounds__(64) void unn_main(const float* __restrict__ xT,
                                               const int2* __restrict__ meta,
                                               void* __restrict__ outsv) {
    __shared__ float Hf[LDSZ / 4];
    char* Hl = (char*)Hf;
    const int lane = threadIdx.x;
    const int p    = lane & 7;
    const int s    = (lane >> 3) & 1;
    const int kq   = lane >> 4;
    int bid = (int)blockIdx.x;
    bid = (bid & 7) * 256 + (bid >> 3);          // XCD swizzle (2048 % 8 == 0, bijective)
    const int net = bid >> 5;
    const int b0  = (bid & 31) * TILE;

    // stage rows 0..129: 1040 float4 chunks, linear mapping (conflict-free)
    for (int i = lane; i < 1040; i += 64) {
        int row = i >> 3, c = i & 7;
        float4 v = *(const float4*)(xT + (size_t)row * NBATCH + b0 + c * 4);
        *(float4*)(Hl + row * ROWB + c * 16) = v;
    }
    __syncthreads();

    const int2* mbase = meta + (size_t)net * 9216 + (s * 4 + kq) * 8;
    const char* Hp = Hl + p * 16;
    float*          o32p = (float*)outsv          + (size_t)net * NOUT * NBATCH + b0 + 4 * p;
    unsigned short* o16p = (unsigned short*)outsv + (size_t)net * NOUT * NBATCH + b0 + 4 * p;

    int4 A[4], B[4], C[4], D[4];

    auto PREF = [&](int4 (&M)[4], int t) {
        const int4* mp = (const int4*)(mbase + (size_t)t * 64);
        #pragma unroll
        for (int j = 0; j < 4; ++j) M[j] = mp[j];
    };

    auto BODY = [&](const int4 (&M)[4], int t) {
        float4 a0 = make_float4(0.f, 0.f, 0.f, 0.f);
        float4 a1 = make_float4(0.f, 0.f, 0.f, 0.f);
        #pragma unroll
        for (int j = 0; j < 4; ++j) {
            int4 m = M[j];
            float4 v0 = *(const float4*)(Hp + m.x);
            float4 v1 = *(const float4*)(Hp + m.z);
            float w0 = __int_as_float(m.y), w1 = __int_as_float(m.w);
            a0.x = fmaf(w0, v0.x, a0.x); a0.y = fmaf(w0, v0.y, a0.y);
            a0.z = fmaf(w0, v0.z, a0.z); a0.w = fmaf(w0, v0.w, a0.w);
            a1.x = fmaf(w1, v1.x, a1.x); a1.y = fmaf(w1, v1.y, a1.y);
            a1.z = fmaf(w1, v1.z, a1.z); a1.w = fmaf(w1, v1.w, a1.w);
        }
        float rx = a0.x + a1.x, ry = a0.y + a1.y, rz = a0.z + a1.z, rw = a0.w + a1.w;
        rx = xor16_add(rx); ry = xor16_add(ry); rz = xor16_add(rz); rw = xor16_add(rw);
        rx = xor32_add(rx); ry = xor32_add(ry); rz = xor32_add(rz); rw = xor32_add(rw);
        rx = fmaxf(rx, 0.01f * rx); ry = fmaxf(ry, 0.01f * ry);
        rz = fmaxf(rz, 0.01f * rz); rw = fmaxf(rw, 0.01f * rw);
        int node = 2 * t + s;
        if (kq == 0) {
            if (node < NHID) {
                *(float4*)(Hl + (130 + node) * ROWB + p * 16) = make_float4(rx, ry, rz, rw);
            } else if (F32OUT) {
                *(float4*)(o32p + (size_t)(node - NHID) * NBATCH) = make_float4(rx, ry, rz, rw);
            } else {
                uint2 u;
                u.x = f2bf(rx) | (f2bf(ry) << 16);
                u.y = f2bf(rz) | (f2bf(rw) << 16);
                *(uint2*)(o16p + (size_t)(node - NHID) * NBATCH) = u;
            }
        }
    };

    PREF(A, 0); PREF(B, 1); PREF(C, 2); PREF(D, 3);
    for (int t = 0; t < NPAIR; t += 4) {          // 144 = 4*36, no tail
        BODY(A, t);     PREF(A, (t + 4 < NPAIR) ? t + 4 : NPAIR - 1);
        BODY(B, t + 1); PREF(B, (t + 5 < NPAIR) ? t + 5 : NPAIR - 1);
        BODY(C, t + 2); PREF(C, (t + 6 < NPAIR) ? t + 6 : NPAIR - 1);
        BODY(D, t + 3); PREF(D, (t + 7 < NPAIR) ? t + 7 : NPAIR - 1);
    }
}

// ---- reduce: out[b][o] = sum_n softmax(nw)[n] * outs[n][o][b] ----
// grid: 512 blocks = (batch-tile 0..15) x (o 0..31), 64 threads
template <bool F32OUT>
__global__ __launch_bounds__(64) void unn_reduce(const float* __restrict__ nw,
                                                 const void* __restrict__ outsv,
                                                 float* __restrict__ out) {
    __shared__ float sw[NETS];
    int tt = threadIdx.x;
    int o  = blockIdx.x & 31;
    int bt = blockIdx.x >> 5;
    float v = nw[tt];
    float m = v;
    #pragma unroll
    for (int off = 32; off; off >>= 1) m = fmaxf(m, __shfl_xor(m, off, 64));
    float e = __expf(v - m);
    float ssum = e;
    #pragma unroll
    for (int off = 32; off; off >>= 1) ssum += __shfl_xor(ssum, off, 64);
    sw[tt] = e / ssum;
    __syncthreads();

    int bb = bt * 64 + tt;
    const float* o32 = (const float*)outsv;
    const unsigned short* o16 = (const unsigned short*)outsv;
    float acc = 0.f;
    #pragma unroll 8
    for (int n = 0; n < NETS; ++n) {
        size_t idx = ((size_t)n * NOUT + o) * NBATCH + bb;
        float val = F32OUT ? o32[idx] : bf2f(o16[idx]);
        acc = fmaf(sw[n], val, acc);
    }
    out[(size_t)bb * NOUT + o] = acc;
}

extern "C" void kernel_launch(void* const* d_in, const int* in_sizes, int n_in,
                              void* d_out, int out_size, void* d_ws, size_t ws_size,
                              hipStream_t stream) {
    const float* x    = (const float*)d_in[0];   // 1024*128
    const float* W    = (const float*)d_in[1];   // 386*288
    const float* nw   = (const float*)d_in[2];   // 64
    const int*   conn = (const int*)d_in[3];     // 64*288*32
    float* out = (float*)d_out;                  // 1024*32

    char* ws = (char*)d_ws;
    int2*  meta = (int2*)(ws);                   // 589,824 * 8 = 4,718,592
    float* xT   = (float*)(ws + 4718592);        // 130*1024*4  =   532,480
    void*  outs = (void*)(ws + 4718592 + 532480);// f32: 8,388,608 | bf16: 4,194,304

    const bool f32path = ws_size >= (size_t)4718592 + 532480 + 8388608;  // 13,639,680

    prep_meta<<<dim3(2304), dim3(256), 0, stream>>>(W, conn, meta);
    prep_xt  <<<dim3(520),  dim3(256), 0, stream>>>(x, xT);
    if (f32path) {
        unn_main<true> <<<dim3(NETS * (NBATCH/TILE)), dim3(64), 0, stream>>>(xT, meta, outs);
        unn_reduce<true> <<<dim3(512), dim3(64), 0, stream>>>(nw, outs, out);
    } else {
        unn_main<false> <<<dim3(NETS * (NBATCH/TILE)), dim3(64), 0, stream>>>(xT, meta, outs);
        unn_reduce<false> <<<dim3(512), dim3(64), 0, stream>>>(nw, outs, out);
    }
}

// Round 9
// 176.136 us; speedup vs baseline: 1.1999x; 1.1999x over previous
//
#include <hip/hip_runtime.h>

#define NETS   64
#define NNODES 288
#define NHID   256
#define NOUT   32
#define KCON   32
#define NBATCH 1024
#define TILE   32                    // batches per block
#define NPAIR  144
#define ROWB   128                   // 32 f32 = one full 32-bank stripe per row
#define LDSZ   (386 * ROWB)          // 49,408 B -> 3 blocks/CU

#if defined(__has_builtin)
#if __has_builtin(__builtin_amdgcn_permlane16_swap)
#define HAVE_PL16 1
#endif
#if __has_builtin(__builtin_amdgcn_permlane32_swap)
#define HAVE_PL32 1
#endif
#endif

__device__ __forceinline__ float xor16_add(float a) {
#ifdef HAVE_PL16
    auto r = __builtin_amdgcn_permlane16_swap(__float_as_uint(a), __float_as_uint(a),
                                              false, false);
    return __uint_as_float(r[0]) + __uint_as_float(r[1]);
#else
    return a + __shfl_xor(a, 16, 64);
#endif
}
__device__ __forceinline__ float xor32_add(float a) {
#ifdef HAVE_PL32
    auto r = __builtin_amdgcn_permlane32_swap(__float_as_uint(a), __float_as_uint(a),
                                              false, false);
    return __uint_as_float(r[0]) + __uint_as_float(r[1]);
#else
    return a + __shfl_xor(a, 32, 64);
#endif
}

__device__ __forceinline__ unsigned f2bf(float f) {
    unsigned b = __float_as_uint(f);
    return (b + 0x7FFFu + ((b >> 16) & 1u)) >> 16;
}
__device__ __forceinline__ float bf2f(unsigned short u) {
    return __uint_as_float(((unsigned)u) << 16);
}

// ---- prep: meta per-lane-contiguous: meta[net][t][s][kq][j] = {idx*ROWB, w_bits} ----
__global__ __launch_bounds__(256) void prep_meta(const float* __restrict__ W,
                                                 const int* __restrict__ conn,
                                                 int2* __restrict__ meta) {
    int g = blockIdx.x * 256 + threadIdx.x;      // 64*288*32 = 589,824 exact
    int net = g / 9216;
    int rem = g - net * 9216;
    int node = rem >> 5, k = rem & 31;
    int idx = conn[g];                           // 0..385
    float w = W[(size_t)idx * NNODES + node];
    int didx = net * 9216 + (node >> 1) * 64 + (node & 1) * 32 + (k >> 3) * 8 + (k & 7);
    meta[didx] = make_int2(idx * ROWB, __float_as_int(w));
}

// ---- prep: safe[net][t] = 1 iff pair t references nothing from pair t-1 ----
// (all 64 slot indices of nodes {2t, 2t+1} are < 128 + 2t)
__global__ __launch_bounds__(256) void prep_safe(const int* __restrict__ conn,
                                                 int* __restrict__ safep) {
    int g = blockIdx.x * 256 + threadIdx.x;      // 64*144 = 9216
    if (g >= NETS * NPAIR) return;
    int net = g / NPAIR, t = g - net * NPAIR;
    const int* cp = conn + ((size_t)net * NNODES + 2 * t) * KCON;
    int mx = 0;
    for (int k = 0; k < 2 * KCON; ++k) mx = max(mx, cp[k]);
    safep[g] = (mx < 128 + 2 * t) ? 1 : 0;
}

// ---- prep: xT[row][batch] f32; rows 0..127 = x^T, 128 = 0.0, 129 = 1.0 ----
__global__ __launch_bounds__(256) void prep_xt(const float* __restrict__ x,
                                               float* __restrict__ xT) {
    int g = blockIdx.x * 256 + threadIdx.x;      // 130*1024 = 133,120 exact
    int r = g >> 10, b = g & 1023;
    float v = (r < 128) ? x[(size_t)b * 128 + r] : ((r == 128) ? 0.0f : 1.0f);
    xT[(size_t)r * NBATCH + b] = v;
}

// ---- main: 1 wave / (net, 32-batch tile); read-ahead past fake dependencies ----
// lane = kq(2b) | s(1b) | p(3b): 8 k-slots per lane, 4 batches per lane (float4)
template <bool F32OUT>
__global__ __launch_bounds__(64) void unn_main(const float* __restrict__ xT,
                                               const int2* __restrict__ meta,
                                               const int* __restrict__ safep,
                                               void* __restrict__ outsv) {
    __shared__ float Hf[LDSZ / 4];
    char* Hl = (char*)Hf;
    const int lane = threadIdx.x;
    const int p    = lane & 7;
    const int s    = (lane >> 3) & 1;
    const int kq   = lane >> 4;
    int bid = (int)blockIdx.x;
    bid = (bid & 7) * 256 + (bid >> 3);          // XCD swizzle (2048 % 8 == 0, bijective)
    const int net = bid >> 5;
    const int b0  = (bid & 31) * TILE;

    const int2* mbase = meta + (size_t)net * 9216 + (s * 4 + kq) * 8;
    const int*  sbase = safep + net * NPAIR;
    const char* Hp = Hl + p * 16;
    float*          o32p = (float*)outsv          + (size_t)net * NOUT * NBATCH + b0 + 4 * p;
    unsigned short* o16p = (unsigned short*)outsv + (size_t)net * NOUT * NBATCH + b0 + 4 * p;

    int4 MA[4], MB[4], MC[4], MD[4];
    int sA, sB, sC, sD;
    float4 V0[8], V1[8];

    auto PREF = [&](int4 (&M)[4], int& sf, int t) {
        const int4* mp = (const int4*)(mbase + (size_t)t * 64);
        #pragma unroll
        for (int j = 0; j < 4; ++j) M[j] = mp[j];
        sf = sbase[t];
    };

    PREF(MA, sA, 0); PREF(MB, sB, 1); PREF(MC, sC, 2); PREF(MD, sD, 3);

    // stage rows 0..129: 1040 float4 chunks, linear mapping (conflict-free)
    for (int i = lane; i < 1040; i += 64) {
        int row = i >> 3, c = i & 7;
        float4 v = *(const float4*)(xT + (size_t)row * NBATCH + b0 + c * 4);
        *(float4*)(Hl + row * ROWB + c * 16) = v;
    }
    __syncthreads();

    auto ISSUE = [&](float4 (&V)[8], const int4 (&M)[4]) {
        #pragma unroll
        for (int j = 0; j < 4; ++j) {
            V[2 * j]     = *(const float4*)(Hp + M[j].x);
            V[2 * j + 1] = *(const float4*)(Hp + M[j].z);
        }
    };

    auto ACT = [&](const float4 (&V)[8], const int4 (&M)[4]) -> float4 {
        float4 a0 = make_float4(0.f, 0.f, 0.f, 0.f);
        float4 a1 = make_float4(0.f, 0.f, 0.f, 0.f);
        #pragma unroll
        for (int j = 0; j < 4; ++j) {
            float w0 = __int_as_float(M[j].y), w1 = __int_as_float(M[j].w);
            a0.x = fmaf(w0, V[2*j].x, a0.x);   a0.y = fmaf(w0, V[2*j].y, a0.y);
            a0.z = fmaf(w0, V[2*j].z, a0.z);   a0.w = fmaf(w0, V[2*j].w, a0.w);
            a1.x = fmaf(w1, V[2*j+1].x, a1.x); a1.y = fmaf(w1, V[2*j+1].y, a1.y);
            a1.z = fmaf(w1, V[2*j+1].z, a1.z); a1.w = fmaf(w1, V[2*j+1].w, a1.w);
        }
        float rx = a0.x + a1.x, ry = a0.y + a1.y, rz = a0.z + a1.z, rw = a0.w + a1.w;
        rx = xor16_add(rx); ry = xor16_add(ry); rz = xor16_add(rz); rw = xor16_add(rw);
        rx = xor32_add(rx); ry = xor32_add(ry); rz = xor32_add(rz); rw = xor32_add(rw);
        rx = fmaxf(rx, 0.01f * rx); ry = fmaxf(ry, 0.01f * ry);
        rz = fmaxf(rz, 0.01f * rz); rw = fmaxf(rw, 0.01f * rw);
        return make_float4(rx, ry, rz, rw);
    };

    auto WRITE = [&](float4 r, int t) {
        int node = 2 * t + s;
        if (kq == 0) {
            if (node < NHID) {
                *(float4*)(Hl + (130 + node) * ROWB + p * 16) = r;
            } else if (F32OUT) {
                *(float4*)(o32p + (size_t)(node - NHID) * NBATCH) = r;
            } else {
                uint2 u;
                u.x = f2bf(r.x) | (f2bf(r.y) << 16);
                u.y = f2bf(r.z) | (f2bf(r.w) << 16);
                *(uint2*)(o16p + (size_t)(node - NHID) * NBATCH) = u;
            }
        }
    };

    ISSUE(V0, MA);
    for (int t = 0; t < NPAIR; t += 4) {          // 144 = 4*36, no tail
        float4 r = ACT(V0, MA);
        if (sB) { ISSUE(V1, MB); WRITE(r, t); } else { WRITE(r, t); ISSUE(V1, MB); }
        PREF(MA, sA, (t + 4 < NPAIR) ? t + 4 : NPAIR - 1);

        r = ACT(V1, MB);
        if (sC) { ISSUE(V0, MC); WRITE(r, t + 1); } else { WRITE(r, t + 1); ISSUE(V0, MC); }
        PREF(MB, sB, (t + 5 < NPAIR) ? t + 5 : NPAIR - 1);

        r = ACT(V0, MC);
        if (sD) { ISSUE(V1, MD); WRITE(r, t + 2); } else { WRITE(r, t + 2); ISSUE(V1, MD); }
        PREF(MC, sC, (t + 6 < NPAIR) ? t + 6 : NPAIR - 1);

        r = ACT(V1, MD);
        if (sA) { ISSUE(V0, MA); WRITE(r, t + 3); } else { WRITE(r, t + 3); ISSUE(V0, MA); }
        PREF(MD, sD, (t + 7 < NPAIR) ? t + 7 : NPAIR - 1);
    }
}

// ---- reduce: out[b][o] = sum_n softmax(nw)[n] * outs[n][o][b] ----
// grid: 512 blocks = (batch-tile 0..15) x (o 0..31), 64 threads
template <bool F32OUT>
__global__ __launch_bounds__(64) void unn_reduce(const float* __restrict__ nw,
                                                 const void* __restrict__ outsv,
                                                 float* __restrict__ out) {
    __shared__ float sw[NETS];
    int tt = threadIdx.x;
    int o  = blockIdx.x & 31;
    int bt = blockIdx.x >> 5;
    float v = nw[tt];
    float m = v;
    #pragma unroll
    for (int off = 32; off; off >>= 1) m = fmaxf(m, __shfl_xor(m, off, 64));
    float e = __expf(v - m);
    float ssum = e;
    #pragma unroll
    for (int off = 32; off; off >>= 1) ssum += __shfl_xor(ssum, off, 64);
    sw[tt] = e / ssum;
    __syncthreads();

    int bb = bt * 64 + tt;
    const float* o32 = (const float*)outsv;
    const unsigned short* o16 = (const unsigned short*)outsv;
    float acc = 0.f;
    #pragma unroll 8
    for (int n = 0; n < NETS; ++n) {
        size_t idx = ((size_t)n * NOUT + o) * NBATCH + bb;
        float val = F32OUT ? o32[idx] : bf2f(o16[idx]);
        acc = fmaf(sw[n], val, acc);
    }
    out[(size_t)bb * NOUT + o] = acc;
}

extern "C" void kernel_launch(void* const* d_in, const int* in_sizes, int n_in,
                              void* d_out, int out_size, void* d_ws, size_t ws_size,
                              hipStream_t stream) {
    const float* x    = (const float*)d_in[0];   // 1024*128
    const float* W    = (const float*)d_in[1];   // 386*288
    const float* nw   = (const float*)d_in[2];   // 64
    const int*   conn = (const int*)d_in[3];     // 64*288*32
    float* out = (float*)d_out;                  // 1024*32

    char* ws = (char*)d_ws;
    int2*  meta  = (int2*)(ws);                        // 589,824 * 8 = 4,718,592
    float* xT    = (float*)(ws + 4718592);             // 130*1024*4  =   532,480
    int*   safep = (int*)(ws + 4718592 + 532480);      // 9216*4      =    36,864
    void*  outs  = (void*)(ws + 4718592 + 532480 + 36864); // f32: 8,388,608 | bf16: 4,194,304

    const bool f32path = ws_size >= (size_t)4718592 + 532480 + 36864 + 8388608; // 13,676,544

    prep_meta<<<dim3(2304), dim3(256), 0, stream>>>(W, conn, meta);
    prep_safe<<<dim3(36),   dim3(256), 0, stream>>>(conn, safep);
    prep_xt  <<<dim3(520),  dim3(256), 0, stream>>>(x, xT);
    if (f32path) {
        unn_main<true> <<<dim3(NETS * (NBATCH/TILE)), dim3(64), 0, stream>>>(xT, meta, safep, outs);
        unn_reduce<true> <<<dim3(512), dim3(64), 0, stream>>>(nw, outs, out);
    } else {
        unn_main<false> <<<dim3(NETS * (NBATCH/TILE)), dim3(64), 0, stream>>>(xT, meta, safep, outs);
        unn_reduce<false> <<<dim3(512), dim3(64), 0, stream>>>(nw, outs, out);
    }
}